// Round 1
// baseline (250.177 us; speedup 1.0000x reference)
//
#include <hip/hip_runtime.h>

#define NN 10000
#define NE 640000
#define D  128

// ---- CSR build ----------------------------------------------------------

__global__ __launch_bounds__(256) void count_kernel(const int* __restrict__ ei,
                                                    const float* __restrict__ ew,
                                                    float* __restrict__ deg,
                                                    int* __restrict__ cnt) {
    int e = blockIdx.x * 256 + threadIdx.x;
    if (e < NE) {
        int c = ei[NE + e];                 // target node
        atomicAdd(&deg[c], ew[e]);
        atomicAdd(&cnt[c], 1);
    }
}

__global__ __launch_bounds__(256) void dinv_kernel(const float* __restrict__ deg,
                                                   float* __restrict__ dinv) {
    int i = blockIdx.x * 256 + threadIdx.x;
    if (i < NN) dinv[i] = rsqrtf(deg[i] + 1.0f);   // +1 = self-loop weight; always > 0
}

// single-block Hillis-Steele scan over 10000 counters -> exclusive rowptr
__global__ __launch_bounds__(1024) void scan_kernel(const int* __restrict__ cnt,
                                                    int* __restrict__ rowptr,
                                                    int* __restrict__ woff) {
    __shared__ int buf[1024];
    __shared__ int carry_s;
    int tid = threadIdx.x;
    if (tid == 0) carry_s = 0;
    __syncthreads();
    for (int base = 0; base < NN; base += 1024) {
        int i = base + tid;
        int v = (i < NN) ? cnt[i] : 0;
        buf[tid] = v;
        __syncthreads();
        for (int off = 1; off < 1024; off <<= 1) {
            int t = (tid >= off) ? buf[tid - off] : 0;
            __syncthreads();
            buf[tid] += t;
            __syncthreads();
        }
        int incl  = buf[tid];
        int carry = carry_s;
        if (i < NN) {
            int excl = carry + incl - v;
            rowptr[i] = excl;
            woff[i]   = excl;
        }
        __syncthreads();
        if (tid == 1023) carry_s = carry + buf[1023];
        __syncthreads();
    }
    if (tid == 0) rowptr[NN] = carry_s;   // == NE
}

__global__ __launch_bounds__(256) void build_kernel(const int* __restrict__ ei,
                                                    const float* __restrict__ ew,
                                                    const float* __restrict__ dinv,
                                                    int* __restrict__ woff,
                                                    int* __restrict__ esrc,
                                                    float* __restrict__ enorm) {
    int e = blockIdx.x * 256 + threadIdx.x;
    if (e < NE) {
        int r = ei[e];
        int c = ei[NE + e];
        int pos = atomicAdd(&woff[c], 1);
        esrc[pos]  = r;
        enorm[pos] = dinv[r] * ew[e] * dinv[c];
    }
}

// ---- dense H = X @ W ----------------------------------------------------
// 16 rows per 128-thread block; thread d owns output column d.

__global__ __launch_bounds__(128) void gemm_kernel(const float* __restrict__ X,
                                                   const float* __restrict__ W,
                                                   float* __restrict__ H) {
    __shared__ float xs[16][D];
    int r0 = blockIdx.x * 16;
    int d  = threadIdx.x;
#pragma unroll
    for (int r = 0; r < 16; ++r) {
        int rr = r0 + r;
        xs[r][d] = (rr < NN) ? X[rr * D + d] : 0.0f;
    }
    __syncthreads();
    float acc[16];
#pragma unroll
    for (int r = 0; r < 16; ++r) acc[r] = 0.0f;
    for (int k = 0; k < D; k += 4) {
        float w0 = W[(k + 0) * D + d];
        float w1 = W[(k + 1) * D + d];
        float w2 = W[(k + 2) * D + d];
        float w3 = W[(k + 3) * D + d];
#pragma unroll
        for (int r = 0; r < 16; ++r) {
            float4 xv = *reinterpret_cast<const float4*>(&xs[r][k]);
            acc[r] = fmaf(xv.x, w0, acc[r]);
            acc[r] = fmaf(xv.y, w1, acc[r]);
            acc[r] = fmaf(xv.z, w2, acc[r]);
            acc[r] = fmaf(xv.w, w3, acc[r]);
        }
    }
#pragma unroll
    for (int r = 0; r < 16; ++r) {
        int rr = r0 + r;
        if (rr < NN) H[rr * D + d] = acc[r];
    }
}

// ---- CSR gather-aggregate + bias + ReLU ---------------------------------
// one block per target node, thread d owns feature d.

__global__ __launch_bounds__(128) void agg_kernel(const float* __restrict__ H,
                                                  const int* __restrict__ rowptr,
                                                  const int* __restrict__ esrc,
                                                  const float* __restrict__ enorm,
                                                  const float* __restrict__ dinv,
                                                  const float* __restrict__ bias,
                                                  float* __restrict__ out) {
    int c = blockIdx.x;
    int d = threadIdx.x;
    int beg = rowptr[c], end = rowptr[c + 1];
    float di  = dinv[c];
    float acc = di * di * H[c * D + d];      // self-loop term
    int j = beg;
    for (; j + 4 <= end; j += 4) {
        int   r0 = esrc[j],     r1 = esrc[j + 1], r2 = esrc[j + 2], r3 = esrc[j + 3];
        float n0 = enorm[j],    n1 = enorm[j + 1], n2 = enorm[j + 2], n3 = enorm[j + 3];
        acc = fmaf(n0, H[r0 * D + d], acc);
        acc = fmaf(n1, H[r1 * D + d], acc);
        acc = fmaf(n2, H[r2 * D + d], acc);
        acc = fmaf(n3, H[r3 * D + d], acc);
    }
    for (; j < end; ++j) acc = fmaf(enorm[j], H[esrc[j] * D + d], acc);
    out[c * D + d] = fmaxf(acc + bias[d], 0.0f);
}

// ---- launch -------------------------------------------------------------

extern "C" void kernel_launch(void* const* d_in, const int* in_sizes, int n_in,
                              void* d_out, int out_size, void* d_ws, size_t ws_size,
                              hipStream_t stream) {
    const float* x  = (const float*)d_in[0];
    const int*   ei = (const int*)  d_in[1];   // [2, NE]: row = ei[e], col = ei[NE+e]
    const float* ew = (const float*)d_in[2];
    const float* W1 = (const float*)d_in[3];
    const float* b1 = (const float*)d_in[4];
    const float* W2 = (const float*)d_in[5];
    const float* b2 = (const float*)d_in[6];
    float* out = (float*)d_out;

    char* ws = (char*)d_ws;
    size_t off = 0;
    auto alloc = [&](size_t bytes) {
        void* p = ws + off;
        off = (off + bytes + 255) & ~(size_t)255;
        return p;
    };
    float* deg    = (float*)alloc(NN * 4);
    int*   cnt    = (int*)  alloc(NN * 4);
    float* dinv   = (float*)alloc(NN * 4);
    int*   rowptr = (int*)  alloc((NN + 1) * 4);
    int*   woff   = (int*)  alloc(NN * 4);
    int*   esrc   = (int*)  alloc((size_t)NE * 4);
    float* enorm  = (float*)alloc((size_t)NE * 4);
    float* h      = (float*)alloc((size_t)NN * D * 4);
    float* g      = (float*)alloc((size_t)NN * D * 4);

    // zero deg+cnt (contiguous region; ws is NOT re-poisoned between replays)
    hipMemsetAsync(deg, 0, (size_t)((char*)dinv - (char*)deg), stream);

    count_kernel<<<(NE + 255) / 256, 256, 0, stream>>>(ei, ew, deg, cnt);
    dinv_kernel <<<(NN + 255) / 256, 256, 0, stream>>>(deg, dinv);
    scan_kernel <<<1, 1024, 0, stream>>>(cnt, rowptr, woff);
    build_kernel<<<(NE + 255) / 256, 256, 0, stream>>>(ei, ew, dinv, woff, esrc, enorm);

    gemm_kernel<<<NN / 16, 128, 0, stream>>>(x, W1, h);
    agg_kernel <<<NN, 128, 0, stream>>>(h, rowptr, esrc, enorm, dinv, b1, g);
    gemm_kernel<<<NN / 16, 128, 0, stream>>>(g, W2, h);
    agg_kernel <<<NN, 128, 0, stream>>>(h, rowptr, esrc, enorm, dinv, b2, out);
}

// Round 2
// 183.125 us; speedup vs baseline: 1.3662x; 1.3662x over previous
//
#include <hip/hip_runtime.h>

#define NN 10000
#define NE 640000
#define D  128

// ---- pass 1: per-target rank via single atomic per edge -----------------

__global__ __launch_bounds__(256) void count_rank_kernel(const int* __restrict__ ei,
                                                         int* __restrict__ cnt,
                                                         int* __restrict__ rank) {
    int e = blockIdx.x * 256 + threadIdx.x;
    if (e < NE) {
        int c = ei[NE + e];                   // target node
        rank[e] = atomicAdd(&cnt[c], 1);
    }
}

// ---- exclusive scan over 10000 counts, single block, 3 barriers ---------

__global__ __launch_bounds__(1024) void scan_kernel(const int* __restrict__ cnt,
                                                    int* __restrict__ rowptr) {
    __shared__ int lds[10240];
    __shared__ int wsum[16];
    int tid = threadIdx.x;
    for (int i = tid; i < 10240; i += 1024) lds[i] = (i < NN) ? cnt[i] : 0;
    __syncthreads();
    int base = tid * 10;
    int s = 0;
#pragma unroll
    for (int k = 0; k < 10; ++k) s += lds[base + k];
    int lane = tid & 63, wid = tid >> 6;
    int v = s;
    for (int off = 1; off < 64; off <<= 1) {
        int t = __shfl_up(v, off);
        if (lane >= off) v += t;
    }
    if (lane == 63) wsum[wid] = v;
    __syncthreads();
    if (wid == 0) {
        int w = (lane < 16) ? wsum[lane] : 0;
        for (int off = 1; off < 16; off <<= 1) {
            int t = __shfl_up(w, off);
            if (lane >= off) w += t;
        }
        if (lane < 16) wsum[lane] = w;
    }
    __syncthreads();
    int run = v - s + (wid > 0 ? wsum[wid - 1] : 0);   // exclusive prefix of this chunk
#pragma unroll
    for (int k = 0; k < 10; ++k) {
        int idx = base + k;
        int val = lds[idx];
        if (idx < NN) rowptr[idx] = run;
        run += val;
    }
    if (tid == 1023) rowptr[NN] = run;                 // == NE
}

// ---- pass 2: atomic-free scatter into CSR order -------------------------

__global__ __launch_bounds__(256) void scatter_kernel(const int* __restrict__ ei,
                                                      const float* __restrict__ ew,
                                                      const int* __restrict__ rowptr,
                                                      const int* __restrict__ rank,
                                                      int* __restrict__ esrc,
                                                      float* __restrict__ wcsr) {
    int e = blockIdx.x * 256 + threadIdx.x;
    if (e < NE) {
        int r = ei[e];
        int c = ei[NE + e];
        int pos = rowptr[c] + rank[e];
        esrc[pos] = r;
        wcsr[pos] = ew[e];
    }
}

// ---- deg -> dinv, wave per node, atomic-free ----------------------------

__global__ __launch_bounds__(256) void degdinv_kernel(const int* __restrict__ rowptr,
                                                      const float* __restrict__ wcsr,
                                                      float* __restrict__ dinv) {
    int node = blockIdx.x * 4 + (threadIdx.x >> 6);
    if (node >= NN) return;
    int lane = threadIdx.x & 63;
    int beg = rowptr[node], end = rowptr[node + 1];
    float s = 0.0f;
    for (int j = beg + lane; j < end; j += 64) s += wcsr[j];
#pragma unroll
    for (int off = 32; off; off >>= 1) s += __shfl_down(s, off);
    if (lane == 0) dinv[node] = rsqrtf(s + 1.0f);      // +1 = self loop
}

// ---- per-edge normalization coefficient ---------------------------------

__global__ __launch_bounds__(256) void enorm_kernel(const int* __restrict__ rowptr,
                                                    const int* __restrict__ esrc,
                                                    const float* __restrict__ wcsr,
                                                    const float* __restrict__ dinv,
                                                    float* __restrict__ enorm) {
    int node = blockIdx.x * 4 + (threadIdx.x >> 6);
    if (node >= NN) return;
    int lane = threadIdx.x & 63;
    int beg = rowptr[node], end = rowptr[node + 1];
    float dc = dinv[node];
    for (int j = beg + lane; j < end; j += 64)
        enorm[j] = dinv[esrc[j]] * wcsr[j] * dc;
}

// ---- dense H = X @ W ----------------------------------------------------

__global__ __launch_bounds__(128) void gemm_kernel(const float* __restrict__ X,
                                                   const float* __restrict__ W,
                                                   float* __restrict__ H) {
    __shared__ float xs[16][D];
    int r0 = blockIdx.x * 16;
    int d  = threadIdx.x;
#pragma unroll
    for (int r = 0; r < 16; ++r) {
        int rr = r0 + r;
        xs[r][d] = (rr < NN) ? X[rr * D + d] : 0.0f;
    }
    __syncthreads();
    float acc[16];
#pragma unroll
    for (int r = 0; r < 16; ++r) acc[r] = 0.0f;
    for (int k = 0; k < D; k += 4) {
        float w0 = W[(k + 0) * D + d];
        float w1 = W[(k + 1) * D + d];
        float w2 = W[(k + 2) * D + d];
        float w3 = W[(k + 3) * D + d];
#pragma unroll
        for (int r = 0; r < 16; ++r) {
            float4 xv = *reinterpret_cast<const float4*>(&xs[r][k]);
            acc[r] = fmaf(xv.x, w0, acc[r]);
            acc[r] = fmaf(xv.y, w1, acc[r]);
            acc[r] = fmaf(xv.z, w2, acc[r]);
            acc[r] = fmaf(xv.w, w3, acc[r]);
        }
    }
#pragma unroll
    for (int r = 0; r < 16; ++r) {
        int rr = r0 + r;
        if (rr < NN) H[rr * D + d] = acc[r];
    }
}

// ---- CSR gather-aggregate + bias + ReLU, LDS-staged edge data -----------

__global__ __launch_bounds__(128) void agg_kernel(const float* __restrict__ H,
                                                  const int* __restrict__ rowptr,
                                                  const int* __restrict__ esrc,
                                                  const float* __restrict__ enorm,
                                                  const float* __restrict__ dinv,
                                                  const float* __restrict__ bias,
                                                  float* __restrict__ out) {
    __shared__ int   s_src[128];
    __shared__ float s_n[128];
    int c = blockIdx.x;
    int d = threadIdx.x;
    int beg = rowptr[c], end = rowptr[c + 1];
    float di  = dinv[c];
    float acc = di * di * H[c * D + d];      // self-loop term
    for (int jb = beg; jb < end; jb += 128) {
        int j = jb + d;
        if (j < end) {
            s_src[d] = esrc[j];
            s_n[d]   = enorm[j];
        }
        __syncthreads();
        int m = min(128, end - jb);
        int jj = 0;
        for (; jj + 4 <= m; jj += 4) {
            acc = fmaf(s_n[jj + 0], H[s_src[jj + 0] * D + d], acc);
            acc = fmaf(s_n[jj + 1], H[s_src[jj + 1] * D + d], acc);
            acc = fmaf(s_n[jj + 2], H[s_src[jj + 2] * D + d], acc);
            acc = fmaf(s_n[jj + 3], H[s_src[jj + 3] * D + d], acc);
        }
        for (; jj < m; ++jj) acc = fmaf(s_n[jj], H[s_src[jj] * D + d], acc);
        __syncthreads();
    }
    out[c * D + d] = fmaxf(acc + bias[d], 0.0f);
}

// ---- launch -------------------------------------------------------------

extern "C" void kernel_launch(void* const* d_in, const int* in_sizes, int n_in,
                              void* d_out, int out_size, void* d_ws, size_t ws_size,
                              hipStream_t stream) {
    const float* x  = (const float*)d_in[0];
    const int*   ei = (const int*)  d_in[1];   // [2, NE]
    const float* ew = (const float*)d_in[2];
    const float* W1 = (const float*)d_in[3];
    const float* b1 = (const float*)d_in[4];
    const float* W2 = (const float*)d_in[5];
    const float* b2 = (const float*)d_in[6];
    float* out = (float*)d_out;

    char* ws = (char*)d_ws;
    size_t off = 0;
    auto alloc = [&](size_t bytes) {
        void* p = ws + off;
        off = (off + bytes + 255) & ~(size_t)255;
        return p;
    };
    int*   cnt    = (int*)  alloc(NN * 4);
    float* dinv   = (float*)alloc(NN * 4);
    int*   rowptr = (int*)  alloc((NN + 1) * 4);
    int*   rank   = (int*)  alloc((size_t)NE * 4);
    int*   esrc   = (int*)  alloc((size_t)NE * 4);
    float* wcsr   = (float*)alloc((size_t)NE * 4);
    float* enorm  = (float*)alloc((size_t)NE * 4);
    float* h      = (float*)alloc((size_t)NN * D * 4);
    float* g      = (float*)alloc((size_t)NN * D * 4);

    hipMemsetAsync(cnt, 0, NN * 4, stream);

    count_rank_kernel<<<(NE + 255) / 256, 256, 0, stream>>>(ei, cnt, rank);
    scan_kernel      <<<1, 1024, 0, stream>>>(cnt, rowptr);
    scatter_kernel   <<<(NE + 255) / 256, 256, 0, stream>>>(ei, ew, rowptr, rank, esrc, wcsr);
    degdinv_kernel   <<<(NN + 3) / 4, 256, 0, stream>>>(rowptr, wcsr, dinv);
    enorm_kernel     <<<(NN + 3) / 4, 256, 0, stream>>>(rowptr, esrc, wcsr, dinv, enorm);

    gemm_kernel<<<NN / 16, 128, 0, stream>>>(x, W1, h);
    agg_kernel <<<NN, 128, 0, stream>>>(h, rowptr, esrc, enorm, dinv, b1, g);
    gemm_kernel<<<NN / 16, 128, 0, stream>>>(g, W2, h);
    agg_kernel <<<NN, 128, 0, stream>>>(h, rowptr, esrc, enorm, dinv, b2, out);
}

// Round 3
// 179.708 us; speedup vs baseline: 1.3921x; 1.0190x over previous
//
#include <hip/hip_runtime.h>

#define NN 10000
#define NE 640000
#define D  128

// ---- zero the counters (rocclr fill kernel costs 42us for 40KB!) --------

__global__ __launch_bounds__(256) void zero_kernel(int* __restrict__ p, int n) {
    int i = blockIdx.x * 256 + threadIdx.x;
    if (i < n) p[i] = 0;
}

// ---- pass 1: per-target rank via single atomic per edge -----------------

__global__ __launch_bounds__(256) void count_rank_kernel(const int* __restrict__ ei,
                                                         int* __restrict__ cnt,
                                                         int* __restrict__ rank) {
    int e = blockIdx.x * 256 + threadIdx.x;
    if (e < NE) {
        int c = ei[NE + e];                   // target node
        rank[e] = atomicAdd(&cnt[c], 1);
    }
}

// ---- exclusive scan over 10000 counts, single block, 3 barriers ---------

__global__ __launch_bounds__(1024) void scan_kernel(const int* __restrict__ cnt,
                                                    int* __restrict__ rowptr) {
    __shared__ int lds[10240];
    __shared__ int wsum[16];
    int tid = threadIdx.x;
    for (int i = tid; i < 10240; i += 1024) lds[i] = (i < NN) ? cnt[i] : 0;
    __syncthreads();
    int base = tid * 10;
    int s = 0;
#pragma unroll
    for (int k = 0; k < 10; ++k) s += lds[base + k];
    int lane = tid & 63, wid = tid >> 6;
    int v = s;
    for (int off = 1; off < 64; off <<= 1) {
        int t = __shfl_up(v, off);
        if (lane >= off) v += t;
    }
    if (lane == 63) wsum[wid] = v;
    __syncthreads();
    if (wid == 0) {
        int w = (lane < 16) ? wsum[lane] : 0;
        for (int off = 1; off < 16; off <<= 1) {
            int t = __shfl_up(w, off);
            if (lane >= off) w += t;
        }
        if (lane < 16) wsum[lane] = w;
    }
    __syncthreads();
    int run = v - s + (wid > 0 ? wsum[wid - 1] : 0);   // exclusive prefix of this chunk
#pragma unroll
    for (int k = 0; k < 10; ++k) {
        int idx = base + k;
        int val = lds[idx];
        if (idx < NN) rowptr[idx] = run;
        run += val;
    }
    if (tid == 1023) rowptr[NN] = run;                 // == NE
}

// ---- pass 2: atomic-free scatter into CSR order -------------------------

__global__ __launch_bounds__(256) void scatter_kernel(const int* __restrict__ ei,
                                                      const float* __restrict__ ew,
                                                      const int* __restrict__ rowptr,
                                                      const int* __restrict__ rank,
                                                      int* __restrict__ esrc,
                                                      float* __restrict__ wcsr) {
    int e = blockIdx.x * 256 + threadIdx.x;
    if (e < NE) {
        int r = ei[e];
        int c = ei[NE + e];
        int pos = rowptr[c] + rank[e];
        esrc[pos] = r;
        wcsr[pos] = ew[e];
    }
}

// ---- deg -> dinv, wave per node, atomic-free ----------------------------

__global__ __launch_bounds__(256) void degdinv_kernel(const int* __restrict__ rowptr,
                                                      const float* __restrict__ wcsr,
                                                      float* __restrict__ dinv) {
    int node = blockIdx.x * 4 + (threadIdx.x >> 6);
    if (node >= NN) return;
    int lane = threadIdx.x & 63;
    int beg = rowptr[node], end = rowptr[node + 1];
    float s = 0.0f;
    for (int j = beg + lane; j < end; j += 64) s += wcsr[j];
#pragma unroll
    for (int off = 32; off; off >>= 1) s += __shfl_down(s, off);
    if (lane == 0) dinv[node] = rsqrtf(s + 1.0f);      // +1 = self loop
}

// ---- dense H = X @ W ----------------------------------------------------

__global__ __launch_bounds__(128) void gemm_kernel(const float* __restrict__ X,
                                                   const float* __restrict__ W,
                                                   float* __restrict__ H) {
    __shared__ float xs[16][D];
    int r0 = blockIdx.x * 16;
    int d  = threadIdx.x;
#pragma unroll
    for (int r = 0; r < 16; ++r) {
        int rr = r0 + r;
        xs[r][d] = (rr < NN) ? X[rr * D + d] : 0.0f;
    }
    __syncthreads();
    float acc[16];
#pragma unroll
    for (int r = 0; r < 16; ++r) acc[r] = 0.0f;
    for (int k = 0; k < D; k += 4) {
        float w0 = W[(k + 0) * D + d];
        float w1 = W[(k + 1) * D + d];
        float w2 = W[(k + 2) * D + d];
        float w3 = W[(k + 3) * D + d];
#pragma unroll
        for (int r = 0; r < 16; ++r) {
            float4 xv = *reinterpret_cast<const float4*>(&xs[r][k]);
            acc[r] = fmaf(xv.x, w0, acc[r]);
            acc[r] = fmaf(xv.y, w1, acc[r]);
            acc[r] = fmaf(xv.z, w2, acc[r]);
            acc[r] = fmaf(xv.w, w3, acc[r]);
        }
    }
#pragma unroll
    for (int r = 0; r < 16; ++r) {
        int rr = r0 + r;
        if (rr < NN) H[rr * D + d] = acc[r];
    }
}

// ---- CSR gather-aggregate + bias + ReLU, norm fused ---------------------
// out[c] = dinv[c]*( sum_e dinv[src]*w*H[src] + dinv[c]*H[c] ) + bias
// one block per target node, thread d owns feature d.

__global__ __launch_bounds__(128) void agg_kernel(const float* __restrict__ H,
                                                  const int* __restrict__ rowptr,
                                                  const int* __restrict__ esrc,
                                                  const float* __restrict__ wcsr,
                                                  const float* __restrict__ dinv,
                                                  const float* __restrict__ bias,
                                                  float* __restrict__ out) {
    __shared__ int   s_src[128];
    __shared__ float s_n[128];
    int c = blockIdx.x;
    int d = threadIdx.x;
    int beg = rowptr[c], end = rowptr[c + 1];
    float di  = dinv[c];
    float acc = di * H[c * D + d];           // self-loop term (x di at epilogue)
    for (int jb = beg; jb < end; jb += 128) {
        int j = jb + d;
        if (j < end) {
            int s = esrc[j];
            s_src[d] = s;
            s_n[d]   = dinv[s] * wcsr[j];    // norm / dinv[c]
        }
        __syncthreads();
        int m = min(128, end - jb);
        int jj = 0;
        for (; jj + 4 <= m; jj += 4) {
            acc = fmaf(s_n[jj + 0], H[s_src[jj + 0] * D + d], acc);
            acc = fmaf(s_n[jj + 1], H[s_src[jj + 1] * D + d], acc);
            acc = fmaf(s_n[jj + 2], H[s_src[jj + 2] * D + d], acc);
            acc = fmaf(s_n[jj + 3], H[s_src[jj + 3] * D + d], acc);
        }
        for (; jj < m; ++jj) acc = fmaf(s_n[jj], H[s_src[jj] * D + d], acc);
        __syncthreads();
    }
    out[c * D + d] = fmaxf(fmaf(di, acc, bias[d]), 0.0f);
}

// ---- launch -------------------------------------------------------------

extern "C" void kernel_launch(void* const* d_in, const int* in_sizes, int n_in,
                              void* d_out, int out_size, void* d_ws, size_t ws_size,
                              hipStream_t stream) {
    const float* x  = (const float*)d_in[0];
    const int*   ei = (const int*)  d_in[1];   // [2, NE]
    const float* ew = (const float*)d_in[2];
    const float* W1 = (const float*)d_in[3];
    const float* b1 = (const float*)d_in[4];
    const float* W2 = (const float*)d_in[5];
    const float* b2 = (const float*)d_in[6];
    float* out = (float*)d_out;

    char* ws = (char*)d_ws;
    size_t off = 0;
    auto alloc = [&](size_t bytes) {
        void* p = ws + off;
        off = (off + bytes + 255) & ~(size_t)255;
        return p;
    };
    int*   cnt    = (int*)  alloc(NN * 4);
    float* dinv   = (float*)alloc(NN * 4);
    int*   rowptr = (int*)  alloc((NN + 1) * 4);
    int*   rank   = (int*)  alloc((size_t)NE * 4);
    int*   esrc   = (int*)  alloc((size_t)NE * 4);
    float* wcsr   = (float*)alloc((size_t)NE * 4);
    float* h      = (float*)alloc((size_t)NN * D * 4);
    float* g      = (float*)alloc((size_t)NN * D * 4);

    zero_kernel      <<<(NN + 255) / 256, 256, 0, stream>>>(cnt, NN);
    count_rank_kernel<<<(NE + 255) / 256, 256, 0, stream>>>(ei, cnt, rank);
    scan_kernel      <<<1, 1024, 0, stream>>>(cnt, rowptr);
    scatter_kernel   <<<(NE + 255) / 256, 256, 0, stream>>>(ei, ew, rowptr, rank, esrc, wcsr);
    degdinv_kernel   <<<(NN + 3) / 4, 256, 0, stream>>>(rowptr, wcsr, dinv);

    gemm_kernel<<<NN / 16, 128, 0, stream>>>(x, W1, h);
    agg_kernel <<<NN, 128, 0, stream>>>(h, rowptr, esrc, wcsr, dinv, b1, g);
    gemm_kernel<<<NN / 16, 128, 0, stream>>>(g, W2, h);
    agg_kernel <<<NN, 128, 0, stream>>>(h, rowptr, esrc, wcsr, dinv, b2, out);
}